// Round 1
// baseline (10944.048 us; speedup 1.0000x reference)
//
#include <hip/hip_runtime.h>
#include <hip/hip_fp16.h>

typedef _Float16 f16;
typedef _Float16 f16x8 __attribute__((ext_vector_type(8)));
typedef float f32x4 __attribute__((ext_vector_type(4)));

#define B_ 64
#define T_ 512
#define I_ 512
#define H_ 1024

// ---------------- conversion kernels ----------------
__global__ void cvt_f16(const float* __restrict__ s, f16* __restrict__ d, long n) {
    long i = ((long)blockIdx.x * blockDim.x + threadIdx.x) * 4;
    long stride = (long)gridDim.x * blockDim.x * 4;
    for (; i < n; i += stride) {
        float4 v = *reinterpret_cast<const float4*>(s + i);
        d[i+0] = (f16)v.x; d[i+1] = (f16)v.y; d[i+2] = (f16)v.z; d[i+3] = (f16)v.w;
    }
}

__global__ void split_f16(const float* __restrict__ s, f16* __restrict__ hi,
                          f16* __restrict__ lo, long n) {
    long i = ((long)blockIdx.x * blockDim.x + threadIdx.x) * 4;
    long stride = (long)gridDim.x * blockDim.x * 4;
    for (; i < n; i += stride) {
        float4 v = *reinterpret_cast<const float4*>(s + i);
        f16 h0=(f16)v.x, h1=(f16)v.y, h2=(f16)v.z, h3=(f16)v.w;
        hi[i+0]=h0; hi[i+1]=h1; hi[i+2]=h2; hi[i+3]=h3;
        lo[i+0]=(f16)(v.x-(float)h0); lo[i+1]=(f16)(v.y-(float)h1);
        lo[i+2]=(f16)(v.z-(float)h2); lo[i+3]=(f16)(v.w-(float)h3);
    }
}

// ---------------- unified MFMA GEMM ----------------
// One wave computes one 16x16 output tile at (mt, nt).
// OUT[m][n] = post( sum_k (Ahi[m][k] (+ Alo[m][k])) * W[n][k] + bias[n] (+ xp[m][n]) )
// W is [Ntot][KT] row-major (B^T layout). All MFMA frags loaded straight from
// global (no LDS, no barriers): A-frag lane l -> row l&15, k = 8*(l>>4)+i;
// W(B)-frag lane l -> col l&15, same k slice. C/D: col=lane&15,
// row=4*(lane>>4)+reg (m89-verified; any symmetric k-permutation cancels).
template<int WPB, int KT, bool HAS_LO, bool STEP, bool SEQ_F16>
__global__ __launch_bounds__(WPB*64) void rnn_gemm(
    const f16* __restrict__ Ahi, long sAhi,
    const f16* __restrict__ Alo, long sAlo,
    const f16* __restrict__ W,
    const float* __restrict__ bias,
    const f16* __restrict__ xp, long sXp,
    void* __restrict__ seq, long sSeq,
    f16* __restrict__ hhi, f16* __restrict__ hlo,
    float* __restrict__ hn)
{
    const int wave = threadIdx.x >> 6;
    const int lane = threadIdx.x & 63;
    const int mt = blockIdx.x;
    const int nt = blockIdx.y * WPB + wave;
    const int m0 = mt << 4, n0 = nt << 4;
    const int r  = lane & 15;
    const int kq = lane >> 4;

    const f16* pa  = Ahi + (long)(m0 + r) * sAhi + kq * 8;
    const f16* pal = nullptr;
    if constexpr (HAS_LO) pal = Alo + (long)(m0 + r) * sAlo + kq * 8;
    const f16* pw  = W + (long)(n0 + r) * KT + kq * 8;

    f32x4 acc = {0.f, 0.f, 0.f, 0.f};
    #pragma unroll 8
    for (int kc = 0; kc < KT; kc += 32) {
        f16x8 af = *reinterpret_cast<const f16x8*>(pa);
        f16x8 wf = *reinterpret_cast<const f16x8*>(pw);
        acc = __builtin_amdgcn_mfma_f32_16x16x32_f16(af, wf, acc, 0, 0, 0);
        if constexpr (HAS_LO) {
            f16x8 alf = *reinterpret_cast<const f16x8*>(pal);
            acc = __builtin_amdgcn_mfma_f32_16x16x32_f16(alf, wf, acc, 0, 0, 0);
            pal += 32;
        }
        pa += 32; pw += 32;
    }

    const int col = lane & 15;
    const int rq  = lane >> 4;
    const int n   = n0 + col;
    const float bv = bias ? bias[n] : 0.f;
    #pragma unroll
    for (int j = 0; j < 4; ++j) {
        const int m = m0 + rq * 4 + j;
        float v = acc[j] + bv;
        if constexpr (STEP) {
            v += (float)xp[(long)m * sXp + n];
            v = tanhf(v);
            if constexpr (SEQ_F16) {
                ((f16*)seq)[(long)m * sSeq + n] = (f16)v;   // doubles as h_hi
            } else {
                ((float*)seq)[(long)m * sSeq + n] = v;
                hhi[m * H_ + n] = (f16)v;
            }
            f16 hi16 = (f16)v;
            hlo[m * H_ + n] = (f16)(v - (float)hi16);
            if (hn) hn[m * H_ + n] = v;
        } else {
            ((f16*)seq)[(long)m * sSeq + n] = (f16)v;
        }
    }
}

// ---------------- host launcher ----------------
extern "C" void kernel_launch(void* const* d_in, const int* in_sizes, int n_in,
                              void* d_out, int out_size, void* d_ws, size_t ws_size,
                              hipStream_t stream) {
    const float* x    = (const float*)d_in[0];
    const float* h0   = (const float*)d_in[1];
    const float* Wxh0 = (const float*)d_in[2];
    const float* Whh0 = (const float*)d_in[3];
    const float* b0   = (const float*)d_in[4];
    const float* Wxh1 = (const float*)d_in[5];
    const float* Whh1 = (const float*)d_in[6];
    const float* b1   = (const float*)d_in[7];
    float* out = (float*)d_out;

    char* ws = (char*)d_ws;
    const long MB = 1024 * 1024;
    f16* Wxh0h = (f16*)(ws + 0);
    f16* Whh0h = (f16*)(ws + 1*MB);
    f16* Wxh1h = (f16*)(ws + 3*MB);
    f16* Whh1h = (f16*)(ws + 5*MB);
    f16* h0hi  = (f16*)(ws + 7*MB);
    f16* h0lo  = (f16*)(ws + 7*MB + 1*262144);
    f16* l0lo  = (f16*)(ws + 7*MB + 2*262144);   // [2][64][1024] ping-pong lo
    f16* l1hi  = (f16*)(ws + 7*MB + 4*262144);   // [2][64][1024]
    f16* l1lo  = (f16*)(ws + 7*MB + 6*262144);   // [2][64][1024]
    f16* xp    = (f16*)(ws + 9*MB);              // [B*T][H] f16, 64 MB
    f16* out0  = (f16*)(ws + 73*MB);             // [B][T][H] f16, 64 MB (= layer0 h_hi)
    f16* xh    = (f16*)(ws + 137*MB);            // x as f16, 32 MB

    // weight / input conversions
    cvt_f16<<<512, 256, 0, stream>>>(Wxh0, Wxh0h, (long)H_*I_);
    cvt_f16<<<512, 256, 0, stream>>>(Whh0, Whh0h, (long)H_*H_);
    cvt_f16<<<512, 256, 0, stream>>>(Wxh1, Wxh1h, (long)H_*H_);
    cvt_f16<<<512, 256, 0, stream>>>(Whh1, Whh1h, (long)H_*H_);
    cvt_f16<<<4096, 256, 0, stream>>>(x, xh, (long)B_*T_*I_);
    split_f16<<<128, 256, 0, stream>>>(h0, h0hi, h0lo, 2L*B_*H_);

    const long SEQ = (long)T_ * H_;   // 524288
    const int  HB  = B_ * H_;         // 65536

    // xproj0 = xh @ Wxh0^T + b0 -> xp
    rnn_gemm<4, I_, false, false, true><<<dim3((B_*T_)/16, H_/64), 256, 0, stream>>>(
        xh, I_, nullptr, 0, Wxh0h, b0, nullptr, 0, xp, H_, nullptr, nullptr, nullptr);

    // layer 0 scan: h_t = tanh(xp_t + h_{t-1} @ Whh0^T); seq out = out0 (f16 = h_hi)
    for (int t = 0; t < T_; ++t) {
        const f16* ahi = t ? (out0 + (long)(t-1)*H_) : h0hi;
        const long sahi = t ? SEQ : H_;
        const f16* alo = t ? (l0lo + ((t-1)&1)*HB) : h0lo;
        rnn_gemm<1, H_, true, true, true><<<dim3(B_/16, H_/16), 64, 0, stream>>>(
            ahi, sahi, alo, H_, Whh0h, nullptr,
            xp + (long)t*H_, SEQ,
            out0 + (long)t*H_, SEQ,
            nullptr, l0lo + (t&1)*HB,
            (t == T_-1) ? (out + (long)B_*T_*H_) : nullptr);
    }

    // xproj1 = out0 @ Wxh1^T + b1 -> xp (reuse buffer)
    rnn_gemm<4, H_, false, false, true><<<dim3((B_*T_)/16, H_/64), 256, 0, stream>>>(
        out0, H_, nullptr, 0, Wxh1h, b1, nullptr, 0, xp, H_, nullptr, nullptr, nullptr);

    // layer 1 scan: seq out = d_out (fp32)
    for (int t = 0; t < T_; ++t) {
        const f16* ahi = t ? (l1hi + ((t-1)&1)*HB) : (h0hi + HB);
        const f16* alo = t ? (l1lo + ((t-1)&1)*HB) : (h0lo + HB);
        rnn_gemm<1, H_, true, true, false><<<dim3(B_/16, H_/16), 64, 0, stream>>>(
            ahi, H_, alo, H_, Whh1h, nullptr,
            xp + (long)t*H_, SEQ,
            out + (long)t*H_, SEQ,
            l1hi + (t&1)*HB, l1lo + (t&1)*HB,
            (t == T_-1) ? (out + (long)B_*T_*H_ + HB) : nullptr);
    }
}

// Round 2
// 8309.094 us; speedup vs baseline: 1.3171x; 1.3171x over previous
//
#include <hip/hip_runtime.h>
#include <hip/hip_fp16.h>

typedef _Float16 f16;
typedef _Float16 f16x8 __attribute__((ext_vector_type(8)));
typedef float f32x4 __attribute__((ext_vector_type(4)));

#define B_ 64
#define T_ 512
#define I_ 512
#define H_ 1024
#define HB_ (B_ * H_)
#define NWG_ 192
#define STEPS_ (T_ + 2)

// ---------------- conversion kernels ----------------
__global__ void cvt_f16(const float* __restrict__ s, f16* __restrict__ d, long n) {
    long i = ((long)blockIdx.x * blockDim.x + threadIdx.x) * 4;
    long stride = (long)gridDim.x * blockDim.x * 4;
    for (; i < n; i += stride) {
        float4 v = *reinterpret_cast<const float4*>(s + i);
        d[i+0] = (f16)v.x; d[i+1] = (f16)v.y; d[i+2] = (f16)v.z; d[i+3] = (f16)v.w;
    }
}

// h0[0] -> h0 ring slot 1 (hi/lo), h0[1] -> h1 ring slot 1 (hi/lo)
__global__ void init_h0(const float* __restrict__ h0,
                        f16* __restrict__ h0hi, f16* __restrict__ h0lo,
                        f16* __restrict__ h1hi, f16* __restrict__ h1lo) {
    int i = blockIdx.x * blockDim.x + threadIdx.x;  // 0..HB_-1
    float v = h0[i];
    f16 hi = (f16)v;
    h0hi[HB_ + i] = hi; h0lo[HB_ + i] = (f16)(v - (float)hi);
    float w = h0[HB_ + i];
    f16 wh = (f16)w;
    h1hi[HB_ + i] = wh; h1lo[HB_ + i] = (f16)(w - (float)wh);
}

// ---------------- batch MFMA GEMM (round-0 proven, STEP=false path only) ----------------
template<int WPB, int KT, bool HAS_LO, bool STEP, bool SEQ_F16>
__global__ __launch_bounds__(WPB*64) void rnn_gemm(
    const f16* __restrict__ Ahi, long sAhi,
    const f16* __restrict__ Alo, long sAlo,
    const f16* __restrict__ W,
    const float* __restrict__ bias,
    const f16* __restrict__ xp, long sXp,
    void* __restrict__ seq, long sSeq,
    f16* __restrict__ hhi, f16* __restrict__ hlo,
    float* __restrict__ hn)
{
    const int wave = threadIdx.x >> 6;
    const int lane = threadIdx.x & 63;
    const int mt = blockIdx.x;
    const int nt = blockIdx.y * WPB + wave;
    const int m0 = mt << 4, n0 = nt << 4;
    const int r  = lane & 15;
    const int kq = lane >> 4;

    const f16* pa  = Ahi + (long)(m0 + r) * sAhi + kq * 8;
    const f16* pal = nullptr;
    if constexpr (HAS_LO) pal = Alo + (long)(m0 + r) * sAlo + kq * 8;
    const f16* pw  = W + (long)(n0 + r) * KT + kq * 8;

    f32x4 acc = {0.f, 0.f, 0.f, 0.f};
    #pragma unroll 8
    for (int kc = 0; kc < KT; kc += 32) {
        f16x8 af = *reinterpret_cast<const f16x8*>(pa);
        f16x8 wf = *reinterpret_cast<const f16x8*>(pw);
        acc = __builtin_amdgcn_mfma_f32_16x16x32_f16(af, wf, acc, 0, 0, 0);
        if constexpr (HAS_LO) {
            f16x8 alf = *reinterpret_cast<const f16x8*>(pal);
            acc = __builtin_amdgcn_mfma_f32_16x16x32_f16(alf, wf, acc, 0, 0, 0);
            pal += 32;
        }
        pa += 32; pw += 32;
    }

    const int col = lane & 15;
    const int rq  = lane >> 4;
    const int n   = n0 + col;
    const float bv = bias ? bias[n] : 0.f;
    #pragma unroll
    for (int j = 0; j < 4; ++j) {
        const int m = m0 + rq * 4 + j;
        float v = acc[j] + bv;
        if constexpr (STEP) {
            v += (float)xp[(long)m * sXp + n];
            v = tanhf(v);
            ((f16*)seq)[(long)m * sSeq + n] = (f16)v;
        } else {
            ((f16*)seq)[(long)m * sSeq + n] = (f16)v;
        }
    }
}

// ---------------- persistent pipelined scan ----------------
// 192 WGs x 256 threads. grp 0: out0[s] = tanh(xp0[s] + h0@Whh0^T)
//                        grp 1: xp1[s-1] = out0[s-1]@Wxh1^T + b1
//                        grp 2: out1[s-2] = tanh(xp1[s-2] + h1@Whh1^T)
// Each WG: 1 m-tile (16 batch rows) x 4 n-tiles (64 cols). Wave w owns
// K-quarter [256w,256w+256): W slice = 32 x f16x8 = 128 VGPRs, loaded once.
// Split-K partials reduced via LDS; wave t finalizes tile t (post-op + stores).
// One device-scope barrier per step (cumulative counter, no reset).
__global__ void __launch_bounds__(256, 1) rnn_scan(
    const f16* __restrict__ Whh0, const f16* __restrict__ Wxh1, const f16* __restrict__ Whh1,
    const f16* __restrict__ xp0,   // [B][T][H] f16 (b0 folded in)
    const float* __restrict__ b1,
    f16* __restrict__ h0hi, f16* __restrict__ h0lo,   // ring [2][B][H]
    f16* __restrict__ h1hi, f16* __restrict__ h1lo,   // ring [2][B][H]
    float* __restrict__ xp1,                          // ring [2][B][H] f32
    float* __restrict__ out,                          // [B][T][H] ++ hn[2][B][H]
    int* __restrict__ barcnt)
{
    __shared__ float part[4][4][256];   // [wave][tile][lane*4+j]
    const int tid  = threadIdx.x;
    const int wave = tid >> 6, lane = tid & 63;
    const int wg   = blockIdx.x;
    const int grp  = wg >> 6;           // 0,1,2 (64 WGs each)
    const int sub  = wg & 63;
    const int m0    = (sub & 3) << 4;
    const int nbase = (sub >> 2) << 6;
    const int r  = lane & 15, kq = lane >> 4;
    const int col = lane & 15, rq = lane >> 4;
    const int kbase = wave << 8;

    const f16* Wmat = (grp == 0) ? Whh0 : (grp == 1) ? Wxh1 : Whh1;

    // register-resident W fragments (static-indexed)
    f16x8 wreg[4][8];
    #pragma unroll
    for (int t = 0; t < 4; ++t)
        #pragma unroll
        for (int it = 0; it < 8; ++it)
            wreg[t][it] = *reinterpret_cast<const f16x8*>(
                Wmat + (long)(nbase + t*16 + r) * H_ + kbase + it*32 + kq*8);

    for (int s = 0; s < STEPS_; ++s) {
        int ts; bool active;
        const f16* ahi; const f16* alo = nullptr;
        if (grp == 0) {
            ts = s; active = (ts < T_);
            const int slot = (ts - 1) & 1;
            ahi = h0hi + slot * HB_; alo = h0lo + slot * HB_;
        } else if (grp == 1) {
            ts = s - 1; active = (ts >= 0) && (ts < T_);
            ahi = h0hi + (ts & 1) * HB_;
        } else {
            ts = s - 2; active = (ts >= 0) && (ts < T_);
            const int slot = (ts - 1) & 1;
            ahi = h1hi + slot * HB_; alo = h1lo + slot * HB_;
        }

        if (active) {
            f32x4 acc[4] = {};
            const f16* pa  = ahi + (long)(m0 + r) * H_ + kbase + kq * 8;
            const f16* pal = alo ? alo + (long)(m0 + r) * H_ + kbase + kq * 8 : nullptr;
            #pragma unroll
            for (int it = 0; it < 8; ++it) {
                f16x8 a = *reinterpret_cast<const f16x8*>(pa + it * 32);
                #pragma unroll
                for (int t = 0; t < 4; ++t)
                    acc[t] = __builtin_amdgcn_mfma_f32_16x16x32_f16(a, wreg[t][it], acc[t], 0, 0, 0);
                if (pal) {
                    f16x8 al = *reinterpret_cast<const f16x8*>(pal + it * 32);
                    #pragma unroll
                    for (int t = 0; t < 4; ++t)
                        acc[t] = __builtin_amdgcn_mfma_f32_16x16x32_f16(al, wreg[t][it], acc[t], 0, 0, 0);
                }
            }
            #pragma unroll
            for (int t = 0; t < 4; ++t)
                *reinterpret_cast<f32x4*>(&part[wave][t][lane * 4]) = acc[t];
        }
        __syncthreads();
        if (active) {
            const int t = wave;                    // wave t finalizes tile t
            const int n = nbase + t * 16 + col;
            f32x4 sm = *reinterpret_cast<f32x4*>(&part[0][t][lane * 4]);
            sm = sm + *reinterpret_cast<f32x4*>(&part[1][t][lane * 4]);
            sm = sm + *reinterpret_cast<f32x4*>(&part[2][t][lane * 4]);
            sm = sm + *reinterpret_cast<f32x4*>(&part[3][t][lane * 4]);
            #pragma unroll
            for (int j = 0; j < 4; ++j) {
                const int b = m0 + rq * 4 + j;
                const long bh = (long)b * H_ + n;
                float v = sm[j];
                if (grp == 0) {
                    v += (float)xp0[(long)b * (T_ * H_) + (long)ts * H_ + n];
                    v = tanhf(v);
                    f16 hi = (f16)v;
                    h0hi[(ts & 1) * HB_ + bh] = hi;
                    h0lo[(ts & 1) * HB_ + bh] = (f16)(v - (float)hi);
                    if (ts == T_ - 1) out[(long)B_ * T_ * H_ + bh] = v;
                } else if (grp == 1) {
                    xp1[(ts & 1) * HB_ + bh] = v + b1[n];
                } else {
                    v += xp1[(ts & 1) * HB_ + bh];
                    v = tanhf(v);
                    f16 hi = (f16)v;
                    h1hi[(ts & 1) * HB_ + bh] = hi;
                    h1lo[(ts & 1) * HB_ + bh] = (f16)(v - (float)hi);
                    out[(long)b * (T_ * H_) + (long)ts * H_ + n] = v;
                    if (ts == T_ - 1) out[(long)B_ * T_ * H_ + HB_ + bh] = v;
                }
            }
        }
        // ---- device-scope grid barrier (cumulative counter) ----
        __syncthreads();   // drains each wave's vmcnt before arrive
        if (tid == 0) {
            __hip_atomic_fetch_add(barcnt, 1, __ATOMIC_ACQ_REL, __HIP_MEMORY_SCOPE_AGENT);
            const int target = NWG_ * (s + 1);
            while (__hip_atomic_load(barcnt, __ATOMIC_RELAXED, __HIP_MEMORY_SCOPE_AGENT) < target) {}
            __builtin_amdgcn_fence(__ATOMIC_ACQUIRE, "agent");
        }
        __syncthreads();
    }
}

// ---------------- host launcher ----------------
extern "C" void kernel_launch(void* const* d_in, const int* in_sizes, int n_in,
                              void* d_out, int out_size, void* d_ws, size_t ws_size,
                              hipStream_t stream) {
    const float* x    = (const float*)d_in[0];
    const float* h0   = (const float*)d_in[1];
    const float* Wxh0 = (const float*)d_in[2];
    const float* Whh0 = (const float*)d_in[3];
    const float* b0   = (const float*)d_in[4];
    const float* Wxh1 = (const float*)d_in[5];
    const float* Whh1 = (const float*)d_in[6];
    const float* b1   = (const float*)d_in[7];
    float* out = (float*)d_out;

    char* ws = (char*)d_ws;
    const long MB = 1024 * 1024;
    f16* Wxh0h = (f16*)(ws + 0);          // 1 MB
    f16* Whh0h = (f16*)(ws + 1*MB);       // 2 MB
    f16* Wxh1h = (f16*)(ws + 3*MB);       // 2 MB
    f16* Whh1h = (f16*)(ws + 5*MB);       // 2 MB
    f16* h0hiR = (f16*)(ws + 7*MB);               // [2][HB] 256 KB
    f16* h0loR = (f16*)(ws + 7*MB + 256*1024);
    f16* h1hiR = (f16*)(ws + 7*MB + 512*1024);
    f16* h1loR = (f16*)(ws + 7*MB + 768*1024);
    float* xp1R = (float*)(ws + 8*MB);            // [2][HB] f32, 512 KB
    int* barcnt = (int*)(ws + 9*MB);              // 4 B
    f16* xp0   = (f16*)(ws + 16*MB);              // [B][T][H] f16, 64 MB
    f16* xh    = (f16*)(ws + 80*MB);              // [B][T][I] f16, 32 MB

    cvt_f16<<<512, 256, 0, stream>>>(Wxh0, Wxh0h, (long)H_*I_);
    cvt_f16<<<512, 256, 0, stream>>>(Whh0, Whh0h, (long)H_*H_);
    cvt_f16<<<512, 256, 0, stream>>>(Wxh1, Wxh1h, (long)H_*H_);
    cvt_f16<<<512, 256, 0, stream>>>(Whh1, Whh1h, (long)H_*H_);
    cvt_f16<<<4096, 256, 0, stream>>>(x, xh, (long)B_*T_*I_);
    init_h0<<<HB_/256, 256, 0, stream>>>(h0, h0hiR, h0loR, h1hiR, h1loR);
    hipMemsetAsync(barcnt, 0, sizeof(int), stream);

    // xp0 = xh @ Wxh0^T + b0   ([B*T][H] f16, row = b*T + t)
    rnn_gemm<4, I_, false, false, true><<<dim3((B_*T_)/16, H_/64), 256, 0, stream>>>(
        xh, I_, nullptr, 0, Wxh0h, b0, nullptr, 0, xp0, H_, nullptr, nullptr, nullptr);

    void* args[] = { (void*)&Whh0h, (void*)&Wxh1h, (void*)&Whh1h, (void*)&xp0,
                     (void*)&b1, (void*)&h0hiR, (void*)&h0loR, (void*)&h1hiR,
                     (void*)&h1loR, (void*)&xp1R, (void*)&out, (void*)&barcnt };
    hipLaunchCooperativeKernel((void*)rnn_scan, dim3(NWG_), dim3(256), args, 0, stream);
}

// Round 4
// 6349.812 us; speedup vs baseline: 1.7235x; 1.3086x over previous
//
#include <hip/hip_runtime.h>
#include <hip/hip_fp16.h>

typedef _Float16 f16;
typedef _Float16 f16x8 __attribute__((ext_vector_type(8)));
typedef float f32x4 __attribute__((ext_vector_type(4)));

#define B_ 64
#define T_ 512
#define I_ 512
#define H_ 1024
#define HB_ (B_ * H_)
#define NWG_ 192
#define STEPS_ (T_ + 2)

// ---------------- conversion kernels ----------------
__global__ void cvt_f16(const float* __restrict__ s, f16* __restrict__ d, long n) {
    long i = ((long)blockIdx.x * blockDim.x + threadIdx.x) * 4;
    long stride = (long)gridDim.x * blockDim.x * 4;
    for (; i < n; i += stride) {
        float4 v = *reinterpret_cast<const float4*>(s + i);
        d[i+0] = (f16)v.x; d[i+1] = (f16)v.y; d[i+2] = (f16)v.z; d[i+3] = (f16)v.w;
    }
}

// h0[0] -> h0 ring slot 1 (hi/lo), h0[1] -> h1 ring slot 1 (hi/lo)
__global__ void init_h0(const float* __restrict__ h0,
                        f16* __restrict__ h0hi, f16* __restrict__ h0lo,
                        f16* __restrict__ h1hi, f16* __restrict__ h1lo) {
    int i = blockIdx.x * blockDim.x + threadIdx.x;  // 0..HB_-1
    float v = h0[i];
    f16 hi = (f16)v;
    h0hi[HB_ + i] = hi; h0lo[HB_ + i] = (f16)(v - (float)hi);
    float w = h0[HB_ + i];
    f16 wh = (f16)w;
    h1hi[HB_ + i] = wh; h1lo[HB_ + i] = (f16)(w - (float)wh);
}

// ---------------- batch MFMA GEMM (round-0/2 proven) ----------------
template<int WPB, int KT, bool HAS_LO, bool STEP, bool SEQ_F16>
__global__ __launch_bounds__(WPB*64) void rnn_gemm(
    const f16* __restrict__ Ahi, long sAhi,
    const f16* __restrict__ Alo, long sAlo,
    const f16* __restrict__ W,
    const float* __restrict__ bias,
    const f16* __restrict__ xp, long sXp,
    void* __restrict__ seq, long sSeq,
    f16* __restrict__ hhi, f16* __restrict__ hlo,
    float* __restrict__ hn)
{
    const int wave = threadIdx.x >> 6;
    const int lane = threadIdx.x & 63;
    const int mt = blockIdx.x;
    const int nt = blockIdx.y * WPB + wave;
    const int m0 = mt << 4, n0 = nt << 4;
    const int r  = lane & 15;
    const int kq = lane >> 4;

    const f16* pa  = Ahi + (long)(m0 + r) * sAhi + kq * 8;
    const f16* pal = nullptr;
    if constexpr (HAS_LO) pal = Alo + (long)(m0 + r) * sAlo + kq * 8;
    const f16* pw  = W + (long)(n0 + r) * KT + kq * 8;

    f32x4 acc = {0.f, 0.f, 0.f, 0.f};
    #pragma unroll 8
    for (int kc = 0; kc < KT; kc += 32) {
        f16x8 af = *reinterpret_cast<const f16x8*>(pa);
        f16x8 wf = *reinterpret_cast<const f16x8*>(pw);
        acc = __builtin_amdgcn_mfma_f32_16x16x32_f16(af, wf, acc, 0, 0, 0);
        if constexpr (HAS_LO) {
            f16x8 alf = *reinterpret_cast<const f16x8*>(pal);
            acc = __builtin_amdgcn_mfma_f32_16x16x32_f16(alf, wf, acc, 0, 0, 0);
            pal += 32;
        }
        pa += 32; pw += 32;
    }

    const int col = lane & 15;
    const int rq  = lane >> 4;
    const int n   = n0 + col;
    const float bv = bias ? bias[n] : 0.f;
    #pragma unroll
    for (int j = 0; j < 4; ++j) {
        const int m = m0 + rq * 4 + j;
        float v = acc[j] + bv;
        if constexpr (STEP) {
            v += (float)xp[(long)m * sXp + n];
            v = tanhf(v);
            ((f16*)seq)[(long)m * sSeq + n] = (f16)v;
        } else {
            ((f16*)seq)[(long)m * sSeq + n] = (f16)v;
        }
    }
}

// ---------------- persistent pipelined scan ----------------
// 192 WGs x 256 threads, 3 pipeline groups of 64 WGs:
//   grp0: h0[s]   = tanh(xp0[s]   + h0[s-1]@Whh0^T)
//   grp1: xp1[s-1]= out0[s-1]@Wxh1^T + b1
//   grp2: h1[s-2] = tanh(xp1[s-2] + h1[s-3]@Whh1^T)
// Each WG: 16 batch rows x 64 cols; wave w owns K-quarter (W slice in 128 VGPRs).
// Barrier: per-WG padded flag (monotone step count) published with a release
// fence (wbl2 drains the whole WG's dirty L2 after __syncthreads' vmcnt drain),
// 192 threads poll the 192 flags in parallel, acquire fence (L1+L2 inv; L1 is
// CU-shared so tid0's fence covers all 4 waves), __syncthreads.
__global__ void __launch_bounds__(256, 1) rnn_scan(
    const f16* __restrict__ Whh0, const f16* __restrict__ Wxh1, const f16* __restrict__ Whh1,
    const f16* __restrict__ xp0,   // [B][T][H] f16 (b0 folded in)
    const float* __restrict__ b1,
    f16* __restrict__ h0hi, f16* __restrict__ h0lo,   // ring [2][B][H]
    f16* __restrict__ h1hi, f16* __restrict__ h1lo,   // ring [2][B][H]
    float* __restrict__ xp1,                          // ring [2][B][H] f32
    float* __restrict__ out,                          // [B][T][H] ++ hn[2][B][H]
    int* __restrict__ flags)
{
    __shared__ float part[4][4][256];   // [wave][tile][lane*4+j]
    const int tid  = threadIdx.x;
    const int wave = tid >> 6, lane = tid & 63;
    const int wg   = blockIdx.x;
    const int grp  = wg >> 6;           // 0,1,2 (64 WGs each)
    const int sub  = wg & 63;
    const int m0    = (sub & 3) << 4;
    const int nbase = (sub >> 2) << 6;
    const int r  = lane & 15, kq = lane >> 4;
    const int col = lane & 15, rq = lane >> 4;
    const int kbase = wave << 8;

    const f16* Wmat = (grp == 0) ? Whh0 : (grp == 1) ? Wxh1 : Whh1;

    // register-resident W fragments (static-indexed)
    f16x8 wreg[4][8];
    #pragma unroll
    for (int t = 0; t < 4; ++t)
        #pragma unroll
        for (int it = 0; it < 8; ++it)
            wreg[t][it] = *reinterpret_cast<const f16x8*>(
                Wmat + (long)(nbase + t*16 + r) * H_ + kbase + it*32 + kq*8);

    for (int s = 0; s < STEPS_; ++s) {
        int ts; bool active;
        const f16* ahi; const f16* alo = nullptr;
        if (grp == 0) {
            ts = s; active = (ts < T_);
            const int slot = (ts - 1) & 1;
            ahi = h0hi + slot * HB_; alo = h0lo + slot * HB_;
        } else if (grp == 1) {
            ts = s - 1; active = (ts >= 0) && (ts < T_);
            ahi = h0hi + (ts & 1) * HB_;
        } else {
            ts = s - 2; active = (ts >= 0) && (ts < T_);
            const int slot = (ts - 1) & 1;
            ahi = h1hi + slot * HB_; alo = h1lo + slot * HB_;
        }

        if (active) {
            f32x4 acc[4] = {};
            const f16* pa  = ahi + (long)(m0 + r) * H_ + kbase + kq * 8;
            const f16* pal = alo ? alo + (long)(m0 + r) * H_ + kbase + kq * 8 : nullptr;
            #pragma unroll
            for (int it = 0; it < 8; ++it) {
                f16x8 a = *reinterpret_cast<const f16x8*>(pa + it * 32);
                #pragma unroll
                for (int t = 0; t < 4; ++t)
                    acc[t] = __builtin_amdgcn_mfma_f32_16x16x32_f16(a, wreg[t][it], acc[t], 0, 0, 0);
                if (pal) {
                    f16x8 al = *reinterpret_cast<const f16x8*>(pal + it * 32);
                    #pragma unroll
                    for (int t = 0; t < 4; ++t)
                        acc[t] = __builtin_amdgcn_mfma_f32_16x16x32_f16(al, wreg[t][it], acc[t], 0, 0, 0);
                }
            }
            #pragma unroll
            for (int t = 0; t < 4; ++t)
                *reinterpret_cast<f32x4*>(&part[wave][t][lane * 4]) = acc[t];
        }
        __syncthreads();
        if (active) {
            const int t = wave;                    // wave t finalizes tile t
            const int n = nbase + t * 16 + col;
            f32x4 sm = *reinterpret_cast<f32x4*>(&part[0][t][lane * 4]);
            sm = sm + *reinterpret_cast<f32x4*>(&part[1][t][lane * 4]);
            sm = sm + *reinterpret_cast<f32x4*>(&part[2][t][lane * 4]);
            sm = sm + *reinterpret_cast<f32x4*>(&part[3][t][lane * 4]);
            #pragma unroll
            for (int j = 0; j < 4; ++j) {
                const int b = m0 + rq * 4 + j;
                const long bh = (long)b * H_ + n;
                float v = sm[j];
                if (grp == 0) {
                    v += (float)xp0[(long)b * (T_ * H_) + (long)ts * H_ + n];
                    v = tanhf(v);
                    f16 hi = (f16)v;
                    h0hi[(ts & 1) * HB_ + bh] = hi;
                    h0lo[(ts & 1) * HB_ + bh] = (f16)(v - (float)hi);
                    if (ts == T_ - 1) out[(long)B_ * T_ * H_ + bh] = v;
                } else if (grp == 1) {
                    xp1[(ts & 1) * HB_ + bh] = v + b1[n];
                } else {
                    v += xp1[(ts & 1) * HB_ + bh];
                    v = tanhf(v);
                    f16 hi = (f16)v;
                    h1hi[(ts & 1) * HB_ + bh] = hi;
                    h1lo[(ts & 1) * HB_ + bh] = (f16)(v - (float)hi);
                    out[(long)b * (T_ * H_) + (long)ts * H_ + n] = v;
                    if (ts == T_ - 1) out[(long)B_ * T_ * H_ + HB_ + bh] = v;
                }
            }
        }
        // ---- grid barrier: per-WG flag + parallel poll (no serialized RMW) ----
        __syncthreads();   // compiler emits vmcnt(0) drain per wave before s_barrier
        if (tid == 0) {
            __builtin_amdgcn_fence(__ATOMIC_RELEASE, "agent");   // wbl2: WG's stores -> LLC
            __hip_atomic_store(&flags[wg * 32], s + 1, __ATOMIC_RELAXED, __HIP_MEMORY_SCOPE_AGENT);
        }
        if (tid < NWG_) {
            while (__hip_atomic_load(&flags[tid * 32], __ATOMIC_RELAXED, __HIP_MEMORY_SCOPE_AGENT) < s + 1) {}
        }
        __syncthreads();
        if (tid == 0) {
            __builtin_amdgcn_fence(__ATOMIC_ACQUIRE, "agent");   // inv L1+L2 before next-step loads
        }
        __syncthreads();
    }
}

// ---------------- host launcher ----------------
extern "C" void kernel_launch(void* const* d_in, const int* in_sizes, int n_in,
                              void* d_out, int out_size, void* d_ws, size_t ws_size,
                              hipStream_t stream) {
    const float* x    = (const float*)d_in[0];
    const float* h0   = (const float*)d_in[1];
    const float* Wxh0 = (const float*)d_in[2];
    const float* Whh0 = (const float*)d_in[3];
    const float* b0   = (const float*)d_in[4];
    const float* Wxh1 = (const float*)d_in[5];
    const float* Whh1 = (const float*)d_in[6];
    const float* b1   = (const float*)d_in[7];
    float* out = (float*)d_out;

    char* ws = (char*)d_ws;
    const long MB = 1024 * 1024;
    f16* Wxh0h = (f16*)(ws + 0);          // 1 MB
    f16* Whh0h = (f16*)(ws + 1*MB);       // 2 MB
    f16* Wxh1h = (f16*)(ws + 3*MB);       // 2 MB
    f16* Whh1h = (f16*)(ws + 5*MB);       // 2 MB
    f16* h0hiR = (f16*)(ws + 7*MB);               // [2][HB] 256 KB each
    f16* h0loR = (f16*)(ws + 7*MB + 256*1024);
    f16* h1hiR = (f16*)(ws + 7*MB + 512*1024);
    f16* h1loR = (f16*)(ws + 7*MB + 768*1024);
    float* xp1R = (float*)(ws + 8*MB);            // [2][HB] f32, 512 KB
    int* flags  = (int*)(ws + 9*MB);              // 192*32 ints, padded
    f16* xp0   = (f16*)(ws + 16*MB);              // [B][T][H] f16, 64 MB
    f16* xh    = (f16*)(ws + 80*MB);              // [B][T][I] f16, 32 MB

    cvt_f16<<<512, 256, 0, stream>>>(Wxh0, Wxh0h, (long)H_*I_);
    cvt_f16<<<512, 256, 0, stream>>>(Whh0, Whh0h, (long)H_*H_);
    cvt_f16<<<512, 256, 0, stream>>>(Wxh1, Wxh1h, (long)H_*H_);
    cvt_f16<<<512, 256, 0, stream>>>(Whh1, Whh1h, (long)H_*H_);
    cvt_f16<<<4096, 256, 0, stream>>>(x, xh, (long)B_*T_*I_);
    init_h0<<<HB_/256, 256, 0, stream>>>(h0, h0hiR, h0loR, h1hiR, h1loR);
    hipMemsetAsync(flags, 0, NWG_ * 32 * sizeof(int), stream);

    // xp0 = xh @ Wxh0^T + b0   ([B*T][H] f16, row = b*T + t)
    rnn_gemm<4, I_, false, false, true><<<dim3((B_*T_)/16, H_/64), 256, 0, stream>>>(
        xh, I_, nullptr, 0, Wxh0h, b0, nullptr, 0, xp0, H_, nullptr, nullptr, nullptr);

    void* args[] = { (void*)&Whh0h, (void*)&Wxh1h, (void*)&Whh1h, (void*)&xp0,
                     (void*)&b1, (void*)&h0hiR, (void*)&h0loR, (void*)&h1hiR,
                     (void*)&h1loR, (void*)&xp1R, (void*)&out, (void*)&flags };
    hipLaunchCooperativeKernel((void*)rnn_scan, dim3(NWG_), dim3(256), args, 0, stream);
}